// Round 10
// baseline (6056.788 us; speedup 1.0000x reference)
//
#include <hip/hip_runtime.h>
#include <cstdint>
#include <math.h>

#define B_ 512
#define S_ 100
#define E_ 256
#define H_ 256

__device__ __forceinline__ float sigmoidf_(float x){ return 1.0f/(1.0f+expf(-x)); }

// fast exp2 / rcp (hardware v_exp_f32 / v_rcp_f32)
__device__ __forceinline__ float exp2_(float x){
#if __has_builtin(__builtin_amdgcn_exp2f)
  return __builtin_amdgcn_exp2f(x);
#else
  float r; asm("v_exp_f32 %0, %1" : "=v"(r) : "v"(x)); return r;
#endif
}
__device__ __forceinline__ float rcp_(float x){
#if __has_builtin(__builtin_amdgcn_rcpf)
  return __builtin_amdgcn_rcpf(x);
#else
  float r; asm("v_rcp_f32 %0, %1" : "=v"(r) : "v"(x)); return r;
#endif
}
// fast tanh: used ONLY in the hot logits inner loops (non-recurrent path).
__device__ __forceinline__ float tanh_(float x){
  const float e = exp2_(fabsf(x) * -2.8853900818f);   // exp(-2|x|)
  const float r = (1.0f - e) * rcp_(1.0f + e);
  return copysignf(r, x);
}

// Threefry-2x32, 20 rounds — matches jax/_src/prng.py lowering exactly.
__device__ __forceinline__ void threefry2x32_(uint32_t k0, uint32_t k1,
                                              uint32_t c0, uint32_t c1,
                                              uint32_t& o0, uint32_t& o1){
  uint32_t ks2 = k0 ^ k1 ^ 0x1BD11BDAu;
  uint32_t x0 = c0 + k0, x1 = c1 + k1;
#define ROT_(x,d) (((x)<<(d))|((x)>>(32-(d))))
#define RND_(r) { x0 += x1; x1 = ROT_(x1,(r)); x1 ^= x0; }
  RND_(13) RND_(15) RND_(26) RND_(6)  x0 += k1;  x1 += ks2 + 1u;
  RND_(17) RND_(29) RND_(16) RND_(24) x0 += ks2; x1 += k0  + 2u;
  RND_(13) RND_(15) RND_(26) RND_(6)  x0 += k0;  x1 += k1  + 3u;
  RND_(17) RND_(29) RND_(16) RND_(24) x0 += k1;  x1 += ks2 + 4u;
  RND_(13) RND_(15) RND_(26) RND_(6)  x0 += ks2; x1 += k0  + 5u;
#undef RND_
#undef ROT_
  o0 = x0; o1 = x1;
}

__device__ __forceinline__ float gumbel_bits_(uint32_t bits){
  const float tiny = 1.175494350822287508e-38f;
  float u = __uint_as_float((bits >> 9) | 0x3f800000u) - 1.0f; // [0,1)
  u = fmaxf(tiny, u + tiny);
  return -logf(-logf(u));
}

__device__ __forceinline__ float wsum_(float v){
  #pragma unroll
  for (int d = 32; d > 0; d >>= 1) v += __shfl_xor(v, d, 64);
  return v;
}
__device__ __forceinline__ float wmax_(float v){
  #pragma unroll
  for (int d = 32; d > 0; d >>= 1) v = fmaxf(v, __shfl_xor(v, d, 64));
  return v;
}

// ---------- prep kernels ----------
// Encoder quad-gate layout (Whh only): Wt[k][4u+q] = Whh[(q*256+u)][k], k in [0,256).
__global__ __launch_bounds__(256) void prep_whQ(const float* __restrict__ Whh,
                                                float* __restrict__ Wt){
  int idx = blockIdx.x*256 + threadIdx.x;            // 1024 blocks -> 256*1024
  int k = idx >> 10, col = idx & 1023;
  int u = col >> 2, q = col & 3;
  Wt[idx] = Whh[(q*256 + u)*256 + k];
}
// Decoder pair-gate layout, Whh ONLY (r5 pattern, half rows):
// Wh[k][gh*512 + u*2 + c] = Whh[(gh*2+c)*256+u][k], k in [0,256).
__global__ __launch_bounds__(256) void prep_wh_pair(const float* __restrict__ Whh,
                                                    float* __restrict__ Wh){
  int idx = blockIdx.x*256 + threadIdx.x;            // 1024 blocks -> 256*1024
  int k = idx >> 10, col = idx & 1023;
  int gh = col >> 9, u = (col >> 1) & 255, c = col & 1;
  int j = (gh*2 + c)*256 + u;
  Wh[idx] = Whh[j*256 + k];
}
// Pq[(g&255)*4 + (g>>8)] = sum_k Wih[g][k] * vec[k]   (serial k, exact)
__global__ __launch_bounds__(256) void prep_P(const float* __restrict__ Wih,
                                              const float* __restrict__ vec,
                                              float* __restrict__ Pq){
  int g = blockIdx.x*256 + threadIdx.x;              // 4 blocks
  const float* wr = Wih + (size_t)g*256;
  float a = 0.f;
  for (int k = 0; k < 256; ++k) a += wr[k]*vec[k];
  Pq[(g & 255)*4 + (g >> 8)] = a;
}
__global__ __launch_bounds__(256) void prep_bias4(const float* __restrict__ b1,
                                                  const float* __restrict__ b2,
                                                  float* __restrict__ o){
  int i = blockIdx.x*256 + threadIdx.x;              // 1024
  int u = i >> 2, q = i & 3, j = q*256 + u;
  o[i] = b1[j] + b2[j];
}
// dst[k][u] = src[u][k]  (256x256)
__global__ __launch_bounds__(256) void transpose256(const float* __restrict__ src,
                                                    float* __restrict__ dst){
  int idx = blockIdx.x*256 + threadIdx.x;            // 65536
  int r = idx >> 8, cc = idx & 255;
  dst[idx] = src[cc*256 + r];
}

// ---------- ref_g / ref_p projection GEMM (unchanged, verified) ----------
__global__ __launch_bounds__(256) void gemm_ref(
    const float* __restrict__ A, const float* __restrict__ Bt,
    const float* __restrict__ bias, float* __restrict__ C)
{
  const int tid = threadIdx.x;
  const int m0 = blockIdx.x * 128, n0 = blockIdx.y * 128;
  __shared__ float As[8][128];
  __shared__ float Bs[8][128];
  float acc[8][8] = {};
  const int tx = tid & 15, ty = tid >> 4;

  for (int k0 = 0; k0 < 256; k0 += 8) {
    {
      const int row = tid >> 1, q = tid & 1;
      const float4 av = *(const float4*)(A + (size_t)(m0+row)*256 + k0 + q*4);
      As[q*4+0][row] = av.x; As[q*4+1][row] = av.y;
      As[q*4+2][row] = av.z; As[q*4+3][row] = av.w;
    }
    {
      const int kk = tid >> 5, nq = tid & 31;
      *(float4*)(&Bs[kk][nq*4]) = *(const float4*)(Bt + (size_t)(k0+kk)*256 + n0 + nq*4);
    }
    __syncthreads();
    #pragma unroll
    for (int k = 0; k < 8; ++k) {
      float a[8], bb[8];
      *(float4*)&a[0]  = *(const float4*)&As[k][ty*8];
      *(float4*)&a[4]  = *(const float4*)&As[k][ty*8+4];
      *(float4*)&bb[0] = *(const float4*)&Bs[k][tx*8];
      *(float4*)&bb[4] = *(const float4*)&Bs[k][tx*8+4];
      #pragma unroll
      for (int i = 0; i < 8; ++i)
        #pragma unroll
        for (int j = 0; j < 8; ++j)
          acc[i][j] += a[i]*bb[j];
    }
    __syncthreads();
  }
  #pragma unroll
  for (int i = 0; i < 8; ++i) {
    const int m = m0 + ty*8 + i;
    #pragma unroll
    for (int j = 0; j < 8; j += 4) {
      const int n = n0 + tx*8 + j;
      float4 o;
      o.x = acc[i][j  ] + bias[n  ];
      o.y = acc[i][j+1] + bias[n+1];
      o.z = acc[i][j+2] + bias[n+2];
      o.w = acc[i][j+3] + bias[n+3];
      *(float4*)(C + (size_t)m*256 + n) = o;
    }
  }
}

// ---------- persistent encoder: 128 blocks x 512 thr, 4 rows/block (r4, verified) ----------
__global__ __launch_bounds__(512) void encoder_kernel(
    const float* __restrict__ Wt, const float* __restrict__ b4,
    const float* __restrict__ P0q, const float* __restrict__ P1q,
    const float* __restrict__ coords,
    float* __restrict__ enc, float* __restrict__ h_out, float* __restrict__ c_out)
{
  const int tid = threadIdx.x;
  const int u   = tid & 255;
  const int kh  = tid >> 8;
  const int b0  = blockIdx.x * 4;

  __shared__ float4 hl4[256];      // h rows 0..3 per k
  __shared__ float4 redE[4][256];  // kh=1 partial gates: [row][u]
  __shared__ float  cl[4][200];

  for (int i = tid; i < 800; i += 512)
    cl[i/200][i%200] = coords[(size_t)b0*200 + i];

  float4 P0v = make_float4(0,0,0,0), P1v = P0v, bq = P0v;
  float c0s = 0.f, c1s = 0.f, c2s = 0.f, c3s = 0.f;
  if (kh == 0) {
    P0v = ((const float4*)P0q)[u];
    P1v = ((const float4*)P1q)[u];
    bq  = ((const float4*)b4)[u];
    hl4[u] = make_float4(0.f,0.f,0.f,0.f);
  }

  const float4* wp = (const float4*)Wt + (kh << 15) + u;
  const float4* hp = hl4 + (kh << 7);
  __syncthreads();

  #pragma unroll 1
  for (int t = 0; t < 100; ++t) {
    // ---- gates h-part: 128 iters, float4 quad-gate weights
    float4 a0 = make_float4(0.f,0.f,0.f,0.f), a1 = a0, a2 = a0, a3 = a0;
    #pragma unroll 8
    for (int k = 0; k < 128; ++k) {
      const float4 w  = wp[k << 8];
      const float4 hv = hp[k];
      a0.x += hv.x*w.x; a0.y += hv.x*w.y; a0.z += hv.x*w.z; a0.w += hv.x*w.w;
      a1.x += hv.y*w.x; a1.y += hv.y*w.y; a1.z += hv.y*w.z; a1.w += hv.y*w.w;
      a2.x += hv.z*w.x; a2.y += hv.z*w.y; a2.z += hv.z*w.z; a2.w += hv.z*w.w;
      a3.x += hv.w*w.x; a3.y += hv.w*w.y; a3.z += hv.w*w.z; a3.w += hv.w*w.w;
    }
    if (kh == 1) {
      redE[0][u] = a0; redE[1][u] = a1; redE[2][u] = a2; redE[3][u] = a3;
    }
    __syncthreads();

    // ---- pointwise (kh=0): gate = xfact + h_lo + h_hi + bias (ocml exact)
    if (kh == 0) {
      float4 h4;
#define PW_(r, AC, CS, HC) { \
      const float4 p = redE[r][u]; \
      const float ca = cl[r][t], cb = cl[r][100+t]; \
      const float gi = (ca*P0v.x + cb*P1v.x) + AC.x + p.x + bq.x; \
      const float gf = (ca*P0v.y + cb*P1v.y) + AC.y + p.y + bq.y; \
      const float gg = (ca*P0v.z + cb*P1v.z) + AC.z + p.z + bq.z; \
      const float go = (ca*P0v.w + cb*P1v.w) + AC.w + p.w + bq.w; \
      const float cN = sigmoidf_(gf)*CS + sigmoidf_(gi)*tanhf(gg); \
      CS = cN; HC = sigmoidf_(go)*tanhf(cN); \
      enc[((size_t)(b0+r)*S_ + t)*H_ + u] = HC; }
      PW_(0, a0, c0s, h4.x)
      PW_(1, a1, c1s, h4.y)
      PW_(2, a2, c2s, h4.z)
      PW_(3, a3, c3s, h4.w)
#undef PW_
      hl4[u] = h4;
      if (t == 99) {
        h_out[(size_t)(b0+0)*256+u] = h4.x; h_out[(size_t)(b0+1)*256+u] = h4.y;
        h_out[(size_t)(b0+2)*256+u] = h4.z; h_out[(size_t)(b0+3)*256+u] = h4.w;
        c_out[(size_t)(b0+0)*256+u] = c0s;  c_out[(size_t)(b0+1)*256+u] = c1s;
        c_out[(size_t)(b0+2)*256+u] = c2s;  c_out[(size_t)(b0+3)*256+u] = c3s;
      }
    }
    __syncthreads();   // orders hl4 write vs next iteration's gates reads
  }
}

// ---------- persistent decoder: 256 blocks x 1024 thr, 2 rows/block ----------
// r9 scaffold + 2-stream ILP in the four streaming loops (gates, qq, q, pq):
// each split into two independent sub-streams with separate accumulators,
// combined at loop exit (doubles loads-in-flight; reorder-class perturbation).
__global__ __launch_bounds__(1024) void decoder_kernel(
    const float* __restrict__ Wh, const float* __restrict__ b4,
    const float* __restrict__ P0q, const float* __restrict__ P1q, const float* __restrict__ Psq,
    const float* __restrict__ coords,
    const float* __restrict__ enc, const float* __restrict__ refg, const float* __restrict__ refp,
    const float* __restrict__ gWqT, const float* __restrict__ gbq, const float* __restrict__ gV,
    const float* __restrict__ pWqT, const float* __restrict__ pbq, const float* __restrict__ pV,
    const float* __restrict__ h_in, const float* __restrict__ c_in,
    float* __restrict__ probs_out, float* __restrict__ idx_out)
{
  const int tid  = threadIdx.x;
  const int u    = tid & 255;
  const int grp  = tid >> 8;       // 0..3
  const int lane = tid & 63;
  const int wv   = tid >> 6;       // 0..15
  const int wv2  = wv & 3;
  const int b0   = blockIdx.x * 2;

  __shared__ float2 hl[256];       // h per k; comps = rows 0,1
  __shared__ float2 redB[3][2][256];
  __shared__ float  cl[2][200];
  __shared__ float  qq_l[2][2][256];   // [khalf][row][u]
  __shared__ float  qp_l[2][2][256];   // [shalf][row][u] — q-context partials
  __shared__ float  pq_l[2][2][256];   // [khalf][row][u]
  __shared__ float  lg_l[2][100];
  __shared__ float  al_l[2][100];
  __shared__ float  lp_l[2][100];
  __shared__ float  gv_l[256], pv_l[256];
  __shared__ int    mask_l[2][100];
  __shared__ int    sel_l[2];

  for (int i = tid; i < 400; i += 1024)
    cl[i/200][i%200] = coords[(size_t)b0*200 + i];
  if (tid < 200) mask_l[tid/100][tid%100] = 0;
  if (tid < 2)   sel_l[tid] = -1;

  const float gbqv = gbq[u];
  const float pbqv = pbq[u];

  float4 P0v = make_float4(0,0,0,0), P1v = P0v, Psv = P0v, bq = P0v;
  float c0s = 0.f, c1s = 0.f;
  if (grp == 0) {
    gv_l[u] = gV[u]; pv_l[u] = pV[u];
    P0v = ((const float4*)P0q)[u];
    P1v = ((const float4*)P1q)[u];
    Psv = ((const float4*)Psq)[u];
    bq = ((const float4*)b4)[u];
    hl[u] = make_float2(h_in[(size_t)(b0+0)*256+u], h_in[(size_t)(b0+1)*256+u]);
    c0s = c_in[(size_t)(b0+0)*256+u];
    c1s = c_in[(size_t)(b0+1)*256+u];
  }
  __syncthreads();

  const int gh = grp >> 1, kh = grp & 1;
  const float2* wpA = (const float2*)Wh + ((size_t)kh << 16) + (gh << 8) + u;
  const float2* wpB = wpA + ((size_t)64 << 9);
  const float2* hp  = hl + (kh << 7);
  const int lrow = grp & 1, lsh = grp >> 1;   // logits decomposition
  const int mrow = grp & 1, mkk = grp >> 1;   // matvec decomposition (row, k/s-half)

  const float* rgL = refg + ((size_t)(b0+lrow)*S_ + lsh*50)*H_;
  const float* rpL = refp + ((size_t)(b0+lrow)*S_ + lsh*50)*H_;

  #pragma unroll 1
  for (int t = 0; t < 100; ++t) {
    // ---- gates GEMM (h-part only): (gh,kh) pair x 128-row half, as TWO
    //      independent 64-row streams (a: rows 0..63, b: rows 64..127)
    float2 aR0 = make_float2(0.f,0.f), aR1 = make_float2(0.f,0.f);
    float2 bR0 = make_float2(0.f,0.f), bR1 = make_float2(0.f,0.f);
    #pragma unroll 8
    for (int k = 0; k < 64; ++k) {
      const float2 wA = wpA[(size_t)k << 9];
      const float2 wB = wpB[(size_t)k << 9];
      const float2 hA = hp[k];
      const float2 hB = hp[64 + k];
      aR0.x += hA.x*wA.x; aR0.y += hA.x*wA.y;
      aR1.x += hA.y*wA.x; aR1.y += hA.y*wA.y;
      bR0.x += hB.x*wB.x; bR0.y += hB.x*wB.y;
      bR1.x += hB.y*wB.x; bR1.y += hB.y*wB.y;
    }
    aR0.x += bR0.x; aR0.y += bR0.y;
    aR1.x += bR1.x; aR1.y += bR1.y;
    if (grp) { redB[grp-1][0][u] = aR0; redB[grp-1][1][u] = aR1; }
    __syncthreads();                               // S1

    // ---- LSTM pointwise (grp0, both rows; x-part rank-2 factored, ocml exact)
    if (grp == 0) {
      const float2 p10 = redB[0][0][u], p20 = redB[1][0][u], p30 = redB[2][0][u];
      const float2 p11 = redB[0][1][u], p21 = redB[1][1][u], p31 = redB[2][1][u];
      float2 h2;
      {
        float xi, xf, xg, xo;
        const int s = sel_l[0];
        if (s < 0) { xi = Psv.x; xf = Psv.y; xg = Psv.z; xo = Psv.w; }
        else {
          const float ca = cl[0][s], cb = cl[0][100+s];
          xi = ca*P0v.x + cb*P1v.x; xf = ca*P0v.y + cb*P1v.y;
          xg = ca*P0v.z + cb*P1v.z; xo = ca*P0v.w + cb*P1v.w;
        }
        const float gi = xi + aR0.x + p10.x + bq.x;
        const float gf = xf + aR0.y + p10.y + bq.y;
        const float gg = xg + p20.x + p30.x + bq.z;
        const float go = xo + p20.y + p30.y + bq.w;
        const float cN = sigmoidf_(gf)*c0s + sigmoidf_(gi)*tanhf(gg);
        c0s = cN; h2.x = sigmoidf_(go)*tanhf(cN);
      }
      {
        float xi, xf, xg, xo;
        const int s = sel_l[1];
        if (s < 0) { xi = Psv.x; xf = Psv.y; xg = Psv.z; xo = Psv.w; }
        else {
          const float ca = cl[1][s], cb = cl[1][100+s];
          xi = ca*P0v.x + cb*P1v.x; xf = ca*P0v.y + cb*P1v.y;
          xg = ca*P0v.z + cb*P1v.z; xo = ca*P0v.w + cb*P1v.w;
        }
        const float gi = xi + aR1.x + p11.x + bq.x;
        const float gf = xf + aR1.y + p11.y + bq.y;
        const float gg = xg + p21.x + p31.x + bq.z;
        const float go = xo + p21.y + p31.y + bq.w;
        const float cN = sigmoidf_(gf)*c1s + sigmoidf_(gi)*tanhf(gg);
        c1s = cN; h2.y = sigmoidf_(go)*tanhf(cN);
      }
      hl[u] = h2;
    }
    __syncthreads();                               // S2

    // ---- qq = g_bq + h @ gWq^T : (row, k-half) x 2 sub-streams of 64
    {
      float qa = (mkk == 0) ? gbqv : 0.f, qb = 0.f;
      const float* hb = (const float*)hl + mrow;
      const float* wq = gWqT + ((size_t)mkk << 15) + u;
      #pragma unroll 8
      for (int k = 0; k < 64; ++k) {
        qa += hb[((mkk << 7) + k) << 1]      * wq[(size_t)k << 8];
        qb += hb[((mkk << 7) + 64 + k) << 1] * wq[(size_t)(64 + k) << 8];
      }
      qq_l[mkk][mrow][u] = qa + qb;
    }
    __syncthreads();                               // S3

    // ---- glimpse logits (row, s-half); mask-skip; qq combined from partials
    {
      const int* mk = mask_l[lrow];
      const float* q0 = qq_l[0][lrow];
      const float* q1 = qq_l[1][lrow];
      for (int is = 0; is < 13; ++is) {
        const int so = is*4 + wv2;
        if (so < 50) {
          const int s = lsh*50 + so;
          if (mk[s]) {
            if (lane == 0) lg_l[lrow][s] = -INFINITY;
          } else {
            float pa = 0.f;
            #pragma unroll
            for (int j = 0; j < 4; ++j) {
              const int hh = lane + 64*j;
              pa += gv_l[hh] * tanh_(q0[hh] + q1[hh] + rgL[(size_t)so*256 + hh]);
            }
            pa = wsum_(pa);
            if (lane == 0) lg_l[lrow][s] = pa;
          }
        }
      }
    }
    __syncthreads();                               // S4

    // ---- glimpse softmax (wave 0 -> row0, wave 8 -> row1)
    if ((wv & 7) == 0) {
      const int row = wv >> 3;
      const float v0 = lg_l[row][lane];
      const float v1 = (lane + 64 < S_) ? lg_l[row][lane + 64] : -INFINITY;
      const float m  = wmax_(fmaxf(v0, v1));
      const float ea = expf(v0 - m);
      const float eb = (lane + 64 < S_) ? expf(v1 - m) : 0.f;
      const float sm = wsum_(ea + eb);
      al_l[row][lane] = ea / sm;
      if (lane + 64 < S_) al_l[row][lane + 64] = eb / sm;
    }
    __syncthreads();                               // S5

    // ---- q = sum_s alpha[s] * enc[b,s,:] : (row, s-half) x 2 sub-streams of 25
    {
      const float* ebp = enc + (size_t)(b0+mrow)*25600 + ((size_t)(mkk*50) << 8) + u;
      const float* av  = al_l[mrow] + mkk*50;
      float aa = 0.f, ab = 0.f;
      #pragma unroll 5
      for (int s = 0; s < 25; ++s) {
        aa += av[s]      * ebp[(size_t)s << 8];
        ab += av[25 + s] * ebp[(size_t)(25 + s) << 8];
      }
      qp_l[mkk][mrow][u] = aa + ab;
    }
    __syncthreads();                               // S6

    // ---- pq = p_bq + q @ pWq^T : (row, k-half) x 2 sub-streams; q[k]=qp0[k]+qp1[k]
    {
      float qa = (mkk == 0) ? pbqv : 0.f, qb = 0.f;
      const float* wq = pWqT + ((size_t)mkk << 15) + u;
      const float* q0 = qp_l[0][mrow] + (mkk << 7);
      const float* q1 = qp_l[1][mrow] + (mkk << 7);
      #pragma unroll 8
      for (int k = 0; k < 64; ++k) {
        qa += (q0[k]      + q1[k])      * wq[(size_t)k << 8];
        qb += (q0[64 + k] + q1[64 + k]) * wq[(size_t)(64 + k) << 8];
      }
      pq_l[mkk][mrow][u] = qa + qb;
    }
    __syncthreads();                               // S7

    // ---- pointer logits: 10*tanh(attn); mask-skip; pq combined from partials
    {
      const int* mk = mask_l[lrow];
      const float* q0 = pq_l[0][lrow];
      const float* q1 = pq_l[1][lrow];
      for (int is = 0; is < 13; ++is) {
        const int so = is*4 + wv2;
        if (so < 50) {
          const int s = lsh*50 + so;
          if (mk[s]) {
            if (lane == 0) lp_l[lrow][s] = -INFINITY;
          } else {
            float pa = 0.f;
            #pragma unroll
            for (int j = 0; j < 4; ++j) {
              const int hh = lane + 64*j;
              pa += pv_l[hh] * tanh_(q0[hh] + q1[hh] + rpL[(size_t)so*256 + hh]);
            }
            pa = wsum_(pa);
            if (lane == 0) lp_l[lrow][s] = 10.0f * tanhf(pa);
          }
        }
      }
    }
    __syncthreads();                               // S8

    // ---- pointer softmax + gumbel-argmax sampling
    if ((wv & 7) == 0) {
      const int row = wv >> 3;
      const int b   = b0 + row;
      const float v0 = lp_l[row][lane];
      const float v1 = (lane + 64 < S_) ? lp_l[row][lane + 64] : -INFINITY;
      const float m  = wmax_(fmaxf(v0, v1));
      const float ea = expf(v0 - m);
      const float eb = (lane + 64 < S_) ? expf(v1 - m) : 0.f;
      const float sm = wsum_(ea + eb);
      float* po = probs_out + ((size_t)t*B_ + b)*S_;
      po[lane] = ea / sm;
      if (lane + 64 < S_) po[lane + 64] = eb / sm;

      uint32_t k0, k1; threefry2x32_(0u, 1u, 0u, (uint32_t)t, k0, k1);
      uint32_t r0, r1;
      threefry2x32_(k0, k1, 0u, (uint32_t)(b*S_ + lane), r0, r1);
      float z0 = v0 + gumbel_bits_(r0 ^ r1);
      float z1 = -INFINITY;
      if (lane + 64 < S_) {
        uint32_t q0b, q1b;
        threefry2x32_(k0, k1, 0u, (uint32_t)(b*S_ + lane + 64), q0b, q1b);
        z1 = v1 + gumbel_bits_(q0b ^ q1b);
      }
      float bvv; int bi;
      if (z1 > z0) { bvv = z1; bi = lane + 64; } else { bvv = z0; bi = lane; }
      #pragma unroll
      for (int d = 32; d > 0; d >>= 1) {
        const float ov = __shfl_xor(bvv, d, 64);
        const int   oi = __shfl_xor(bi, d, 64);
        if (ov > bvv || (ov == bvv && oi < bi)) { bvv = ov; bi = oi; }
      }
      if (lane == 0) {
        idx_out[t*B_ + b] = (float)bi;
        sel_l[row] = bi;
        mask_l[row][bi] = 1;
      }
    }
    __syncthreads();                               // S9
  }
}

extern "C" void kernel_launch(void* const* d_in, const int* in_sizes, int n_in,
                              void* d_out, int out_size, void* d_ws, size_t ws_size,
                              hipStream_t stream) {
  (void)in_sizes; (void)n_in; (void)out_size; (void)ws_size;
  const float* inputs = (const float*)d_in[0];
  const float* emb    = (const float*)d_in[1];
  const float* eWih   = (const float*)d_in[2];
  const float* eWhh   = (const float*)d_in[3];
  const float* ebih   = (const float*)d_in[4];
  const float* ebhh   = (const float*)d_in[5];
  const float* dWih   = (const float*)d_in[6];
  const float* dWhh   = (const float*)d_in[7];
  const float* dbih   = (const float*)d_in[8];
  const float* dbhh   = (const float*)d_in[9];
  const float* gWq    = (const float*)d_in[10];
  const float* gbq    = (const float*)d_in[11];
  const float* gWr    = (const float*)d_in[12];
  const float* gbr    = (const float*)d_in[13];
  const float* gV     = (const float*)d_in[14];
  const float* pWq    = (const float*)d_in[15];
  const float* pbq    = (const float*)d_in[16];
  const float* pWr    = (const float*)d_in[17];
  const float* pbr    = (const float*)d_in[18];
  const float* pV     = (const float*)d_in[19];
  const float* start  = (const float*)d_in[20];

  float* ws = (float*)d_ws;
  size_t o = 0;
  float* WtE  = ws + o; o += (size_t)256*1024;   // encoder quad (Whh only)
  float* WhD  = ws + o; o += (size_t)256*1024;   // decoder pair layout (Whh only)
  float* b4E  = ws + o; o += 1024;
  float* b4D  = ws + o; o += 1024;
  float* PE0  = ws + o; o += 1024;
  float* PE1  = ws + o; o += 1024;
  float* PD0  = ws + o; o += 1024;
  float* PD1  = ws + o; o += 1024;
  float* PDs  = ws + o; o += 1024;
  float* gWqT = ws + o; o += 65536;
  float* pWqT = ws + o; o += 65536;
  float* gWrT = ws + o; o += 65536;
  float* pWrT = ws + o; o += 65536;
  float* enc  = ws + o; o += (size_t)B_*S_*H_;
  float* refg = ws + o; o += (size_t)B_*S_*H_;
  float* refp = ws + o; o += (size_t)B_*S_*H_;
  float* hbuf = ws + o; o += (size_t)B_*H_;
  float* cbuf = ws + o; o += (size_t)B_*H_;

  float* probs = (float*)d_out;
  float* idxo  = probs + (size_t)S_*B_*S_;

  prep_whQ<<<1024,256,0,stream>>>(eWhh, WtE);
  prep_wh_pair<<<1024,256,0,stream>>>(dWhh, WhD);
  prep_P<<<4,256,0,stream>>>(eWih, emb,       PE0);
  prep_P<<<4,256,0,stream>>>(eWih, emb + 256, PE1);
  prep_P<<<4,256,0,stream>>>(dWih, emb,       PD0);
  prep_P<<<4,256,0,stream>>>(dWih, emb + 256, PD1);
  prep_P<<<4,256,0,stream>>>(dWih, start,     PDs);
  prep_bias4<<<4,256,0,stream>>>(ebih, ebhh, b4E);
  prep_bias4<<<4,256,0,stream>>>(dbih, dbhh, b4D);
  transpose256<<<256,256,0,stream>>>(gWq, gWqT);
  transpose256<<<256,256,0,stream>>>(pWq, pWqT);
  transpose256<<<256,256,0,stream>>>(gWr, gWrT);
  transpose256<<<256,256,0,stream>>>(pWr, pWrT);

  encoder_kernel<<<128,512,0,stream>>>(WtE, b4E, PE0, PE1, inputs, enc, hbuf, cbuf);

  gemm_ref<<<dim3(400,2),256,0,stream>>>(enc, gWrT, gbr, refg);
  gemm_ref<<<dim3(400,2),256,0,stream>>>(enc, pWrT, pbr, refp);

  decoder_kernel<<<256,1024,0,stream>>>(WhD, b4D, PD0, PD1, PDs, inputs,
                                        enc, refg, refp,
                                        gWqT, gbq, gV, pWqT, pbq, pV,
                                        hbuf, cbuf, probs, idxo);
}

// Round 11
// 5798.737 us; speedup vs baseline: 1.0445x; 1.0445x over previous
//
#include <hip/hip_runtime.h>
#include <cstdint>
#include <math.h>

#define B_ 512
#define S_ 100
#define E_ 256
#define H_ 256

__device__ __forceinline__ float sigmoidf_(float x){ return 1.0f/(1.0f+expf(-x)); }

// fast exp2 / rcp (hardware v_exp_f32 / v_rcp_f32)
__device__ __forceinline__ float exp2_(float x){
#if __has_builtin(__builtin_amdgcn_exp2f)
  return __builtin_amdgcn_exp2f(x);
#else
  float r; asm("v_exp_f32 %0, %1" : "=v"(r) : "v"(x)); return r;
#endif
}
__device__ __forceinline__ float rcp_(float x){
#if __has_builtin(__builtin_amdgcn_rcpf)
  return __builtin_amdgcn_rcpf(x);
#else
  float r; asm("v_rcp_f32 %0, %1" : "=v"(r) : "v"(x)); return r;
#endif
}
// fast tanh: used ONLY in the hot logits inner loops (non-recurrent path).
__device__ __forceinline__ float tanh_(float x){
  const float e = exp2_(fabsf(x) * -2.8853900818f);   // exp(-2|x|)
  const float r = (1.0f - e) * rcp_(1.0f + e);
  return copysignf(r, x);
}

// Threefry-2x32, 20 rounds — matches jax/_src/prng.py lowering exactly.
__device__ __forceinline__ void threefry2x32_(uint32_t k0, uint32_t k1,
                                              uint32_t c0, uint32_t c1,
                                              uint32_t& o0, uint32_t& o1){
  uint32_t ks2 = k0 ^ k1 ^ 0x1BD11BDAu;
  uint32_t x0 = c0 + k0, x1 = c1 + k1;
#define ROT_(x,d) (((x)<<(d))|((x)>>(32-(d))))
#define RND_(r) { x0 += x1; x1 = ROT_(x1,(r)); x1 ^= x0; }
  RND_(13) RND_(15) RND_(26) RND_(6)  x0 += k1;  x1 += ks2 + 1u;
  RND_(17) RND_(29) RND_(16) RND_(24) x0 += ks2; x1 += k0  + 2u;
  RND_(13) RND_(15) RND_(26) RND_(6)  x0 += k0;  x1 += k1  + 3u;
  RND_(17) RND_(29) RND_(16) RND_(24) x0 += k1;  x1 += ks2 + 4u;
  RND_(13) RND_(15) RND_(26) RND_(6)  x0 += ks2; x1 += k0  + 5u;
#undef RND_
#undef ROT_
  o0 = x0; o1 = x1;
}

__device__ __forceinline__ float gumbel_bits_(uint32_t bits){
  const float tiny = 1.175494350822287508e-38f;
  float u = __uint_as_float((bits >> 9) | 0x3f800000u) - 1.0f; // [0,1)
  u = fmaxf(tiny, u + tiny);
  return -logf(-logf(u));
}

__device__ __forceinline__ float wsum_(float v){
  #pragma unroll
  for (int d = 32; d > 0; d >>= 1) v += __shfl_xor(v, d, 64);
  return v;
}
__device__ __forceinline__ float wmax_(float v){
  #pragma unroll
  for (int d = 32; d > 0; d >>= 1) v = fmaxf(v, __shfl_xor(v, d, 64));
  return v;
}

// ---------- prep kernels ----------
// Encoder quad-gate layout (Whh only): Wt[k][4u+q] = Whh[(q*256+u)][k], k in [0,256).
__global__ __launch_bounds__(256) void prep_whQ(const float* __restrict__ Whh,
                                                float* __restrict__ Wt){
  int idx = blockIdx.x*256 + threadIdx.x;            // 1024 blocks -> 256*1024
  int k = idx >> 10, col = idx & 1023;
  int u = col >> 2, q = col & 3;
  Wt[idx] = Whh[(q*256 + u)*256 + k];
}
// Decoder pair-gate layout, Whh ONLY (r5 pattern, half rows):
// Wh[k][gh*512 + u*2 + c] = Whh[(gh*2+c)*256+u][k], k in [0,256).
__global__ __launch_bounds__(256) void prep_wh_pair(const float* __restrict__ Whh,
                                                    float* __restrict__ Wh){
  int idx = blockIdx.x*256 + threadIdx.x;            // 1024 blocks -> 256*1024
  int k = idx >> 10, col = idx & 1023;
  int gh = col >> 9, u = (col >> 1) & 255, c = col & 1;
  int j = (gh*2 + c)*256 + u;
  Wh[idx] = Whh[j*256 + k];
}
// Pq[(g&255)*4 + (g>>8)] = sum_k Wih[g][k] * vec[k]   (serial k, exact)
__global__ __launch_bounds__(256) void prep_P(const float* __restrict__ Wih,
                                              const float* __restrict__ vec,
                                              float* __restrict__ Pq){
  int g = blockIdx.x*256 + threadIdx.x;              // 4 blocks
  const float* wr = Wih + (size_t)g*256;
  float a = 0.f;
  for (int k = 0; k < 256; ++k) a += wr[k]*vec[k];
  Pq[(g & 255)*4 + (g >> 8)] = a;
}
__global__ __launch_bounds__(256) void prep_bias4(const float* __restrict__ b1,
                                                  const float* __restrict__ b2,
                                                  float* __restrict__ o){
  int i = blockIdx.x*256 + threadIdx.x;              // 1024
  int u = i >> 2, q = i & 3, j = q*256 + u;
  o[i] = b1[j] + b2[j];
}
// dst[k][u] = src[u][k]  (256x256)
__global__ __launch_bounds__(256) void transpose256(const float* __restrict__ src,
                                                    float* __restrict__ dst){
  int idx = blockIdx.x*256 + threadIdx.x;            // 65536
  int r = idx >> 8, cc = idx & 255;
  dst[idx] = src[cc*256 + r];
}

// ---------- ref_g / ref_p projection GEMM (unchanged, verified) ----------
__global__ __launch_bounds__(256) void gemm_ref(
    const float* __restrict__ A, const float* __restrict__ Bt,
    const float* __restrict__ bias, float* __restrict__ C)
{
  const int tid = threadIdx.x;
  const int m0 = blockIdx.x * 128, n0 = blockIdx.y * 128;
  __shared__ float As[8][128];
  __shared__ float Bs[8][128];
  float acc[8][8] = {};
  const int tx = tid & 15, ty = tid >> 4;

  for (int k0 = 0; k0 < 256; k0 += 8) {
    {
      const int row = tid >> 1, q = tid & 1;
      const float4 av = *(const float4*)(A + (size_t)(m0+row)*256 + k0 + q*4);
      As[q*4+0][row] = av.x; As[q*4+1][row] = av.y;
      As[q*4+2][row] = av.z; As[q*4+3][row] = av.w;
    }
    {
      const int kk = tid >> 5, nq = tid & 31;
      *(float4*)(&Bs[kk][nq*4]) = *(const float4*)(Bt + (size_t)(k0+kk)*256 + n0 + nq*4);
    }
    __syncthreads();
    #pragma unroll
    for (int k = 0; k < 8; ++k) {
      float a[8], bb[8];
      *(float4*)&a[0]  = *(const float4*)&As[k][ty*8];
      *(float4*)&a[4]  = *(const float4*)&As[k][ty*8+4];
      *(float4*)&bb[0] = *(const float4*)&Bs[k][tx*8];
      *(float4*)&bb[4] = *(const float4*)&Bs[k][tx*8+4];
      #pragma unroll
      for (int i = 0; i < 8; ++i)
        #pragma unroll
        for (int j = 0; j < 8; ++j)
          acc[i][j] += a[i]*bb[j];
    }
    __syncthreads();
  }
  #pragma unroll
  for (int i = 0; i < 8; ++i) {
    const int m = m0 + ty*8 + i;
    #pragma unroll
    for (int j = 0; j < 8; j += 4) {
      const int n = n0 + tx*8 + j;
      float4 o;
      o.x = acc[i][j  ] + bias[n  ];
      o.y = acc[i][j+1] + bias[n+1];
      o.z = acc[i][j+2] + bias[n+2];
      o.w = acc[i][j+3] + bias[n+3];
      *(float4*)(C + (size_t)m*256 + n) = o;
    }
  }
}

// ---------- persistent encoder: 128 blocks x 512 thr, 4 rows/block (r4, verified) ----------
__global__ __launch_bounds__(512) void encoder_kernel(
    const float* __restrict__ Wt, const float* __restrict__ b4,
    const float* __restrict__ P0q, const float* __restrict__ P1q,
    const float* __restrict__ coords,
    float* __restrict__ enc, float* __restrict__ h_out, float* __restrict__ c_out)
{
  const int tid = threadIdx.x;
  const int u   = tid & 255;
  const int kh  = tid >> 8;
  const int b0  = blockIdx.x * 4;

  __shared__ float4 hl4[256];      // h rows 0..3 per k
  __shared__ float4 redE[4][256];  // kh=1 partial gates: [row][u]
  __shared__ float  cl[4][200];

  for (int i = tid; i < 800; i += 512)
    cl[i/200][i%200] = coords[(size_t)b0*200 + i];

  float4 P0v = make_float4(0,0,0,0), P1v = P0v, bq = P0v;
  float c0s = 0.f, c1s = 0.f, c2s = 0.f, c3s = 0.f;
  if (kh == 0) {
    P0v = ((const float4*)P0q)[u];
    P1v = ((const float4*)P1q)[u];
    bq  = ((const float4*)b4)[u];
    hl4[u] = make_float4(0.f,0.f,0.f,0.f);
  }

  const float4* wp = (const float4*)Wt + (kh << 15) + u;
  const float4* hp = hl4 + (kh << 7);
  __syncthreads();

  #pragma unroll 1
  for (int t = 0; t < 100; ++t) {
    // ---- gates h-part: 128 iters, float4 quad-gate weights
    float4 a0 = make_float4(0.f,0.f,0.f,0.f), a1 = a0, a2 = a0, a3 = a0;
    #pragma unroll 8
    for (int k = 0; k < 128; ++k) {
      const float4 w  = wp[k << 8];
      const float4 hv = hp[k];
      a0.x += hv.x*w.x; a0.y += hv.x*w.y; a0.z += hv.x*w.z; a0.w += hv.x*w.w;
      a1.x += hv.y*w.x; a1.y += hv.y*w.y; a1.z += hv.y*w.z; a1.w += hv.y*w.w;
      a2.x += hv.z*w.x; a2.y += hv.z*w.y; a2.z += hv.z*w.z; a2.w += hv.z*w.w;
      a3.x += hv.w*w.x; a3.y += hv.w*w.y; a3.z += hv.w*w.z; a3.w += hv.w*w.w;
    }
    if (kh == 1) {
      redE[0][u] = a0; redE[1][u] = a1; redE[2][u] = a2; redE[3][u] = a3;
    }
    __syncthreads();

    // ---- pointwise (kh=0): gate = xfact + h_lo + h_hi + bias (ocml exact)
    if (kh == 0) {
      float4 h4;
#define PW_(r, AC, CS, HC) { \
      const float4 p = redE[r][u]; \
      const float ca = cl[r][t], cb = cl[r][100+t]; \
      const float gi = (ca*P0v.x + cb*P1v.x) + AC.x + p.x + bq.x; \
      const float gf = (ca*P0v.y + cb*P1v.y) + AC.y + p.y + bq.y; \
      const float gg = (ca*P0v.z + cb*P1v.z) + AC.z + p.z + bq.z; \
      const float go = (ca*P0v.w + cb*P1v.w) + AC.w + p.w + bq.w; \
      const float cN = sigmoidf_(gf)*CS + sigmoidf_(gi)*tanhf(gg); \
      CS = cN; HC = sigmoidf_(go)*tanhf(cN); \
      enc[((size_t)(b0+r)*S_ + t)*H_ + u] = HC; }
      PW_(0, a0, c0s, h4.x)
      PW_(1, a1, c1s, h4.y)
      PW_(2, a2, c2s, h4.z)
      PW_(3, a3, c3s, h4.w)
#undef PW_
      hl4[u] = h4;
      if (t == 99) {
        h_out[(size_t)(b0+0)*256+u] = h4.x; h_out[(size_t)(b0+1)*256+u] = h4.y;
        h_out[(size_t)(b0+2)*256+u] = h4.z; h_out[(size_t)(b0+3)*256+u] = h4.w;
        c_out[(size_t)(b0+0)*256+u] = c0s;  c_out[(size_t)(b0+1)*256+u] = c1s;
        c_out[(size_t)(b0+2)*256+u] = c2s;  c_out[(size_t)(b0+3)*256+u] = c3s;
      }
    }
    __syncthreads();   // orders hl4 write vs next iteration's gates reads
  }
}

// ---------- persistent decoder: 256 blocks x 1024 thr, 2 rows/block ----------
// r9/r10 scaffold, software-pipelined: gates(t+1) depends only on h(t) (x-part
// factored), so its 128-iter chain is held in registers and split 64/32/32 into
// the qq / q / pq phases (all L2-fast streams; logits phases excluded to avoid
// the r8 in-order-vmcnt hazard with L3 refg/refp loads). Gates chain keeps the
// exact r9 serial order; grp0's partial routes through LDS like the others.
// 8 barriers/step (was 9). Prologue computes gates(0) from the encoder h.
__global__ __launch_bounds__(1024) void decoder_kernel(
    const float* __restrict__ Wh, const float* __restrict__ b4,
    const float* __restrict__ P0q, const float* __restrict__ P1q, const float* __restrict__ Psq,
    const float* __restrict__ coords,
    const float* __restrict__ enc, const float* __restrict__ refg, const float* __restrict__ refp,
    const float* __restrict__ gWqT, const float* __restrict__ gbq, const float* __restrict__ gV,
    const float* __restrict__ pWqT, const float* __restrict__ pbq, const float* __restrict__ pV,
    const float* __restrict__ h_in, const float* __restrict__ c_in,
    float* __restrict__ probs_out, float* __restrict__ idx_out)
{
  const int tid  = threadIdx.x;
  const int u    = tid & 255;
  const int grp  = tid >> 8;       // 0..3
  const int lane = tid & 63;
  const int wv   = tid >> 6;       // 0..15
  const int wv2  = wv & 3;
  const int b0   = blockIdx.x * 2;

  __shared__ float2 hl[256];           // h per k; comps = rows 0,1
  __shared__ float2 redB[4][2][256];   // gate partials: [grp][row][u]
  __shared__ float  cl[2][200];
  __shared__ float  qq_l[2][2][256];   // [khalf][row][u]
  __shared__ float  qp_l[2][2][256];   // [shalf][row][u]
  __shared__ float  pq_l[2][2][256];   // [khalf][row][u]
  __shared__ float  lg_l[2][100];
  __shared__ float  al_l[2][100];
  __shared__ float  lp_l[2][100];
  __shared__ float  gv_l[256], pv_l[256];
  __shared__ int    mask_l[2][100];
  __shared__ int    sel_l[2];

  for (int i = tid; i < 400; i += 1024)
    cl[i/200][i%200] = coords[(size_t)b0*200 + i];
  if (tid < 200) mask_l[tid/100][tid%100] = 0;
  if (tid < 2)   sel_l[tid] = -1;

  const float gbqv = gbq[u];
  const float pbqv = pbq[u];

  float4 P0v = make_float4(0,0,0,0), P1v = P0v, Psv = P0v, bq = P0v;
  float c0s = 0.f, c1s = 0.f;
  if (grp == 0) {
    gv_l[u] = gV[u]; pv_l[u] = pV[u];
    P0v = ((const float4*)P0q)[u];
    P1v = ((const float4*)P1q)[u];
    Psv = ((const float4*)Psq)[u];
    bq = ((const float4*)b4)[u];
    hl[u] = make_float2(h_in[(size_t)(b0+0)*256+u], h_in[(size_t)(b0+1)*256+u]);
    c0s = c_in[(size_t)(b0+0)*256+u];
    c1s = c_in[(size_t)(b0+1)*256+u];
  }
  __syncthreads();

  const int gh = grp >> 1, kh = grp & 1;
  const float2* wp = (const float2*)Wh + ((size_t)kh << 16) + (gh << 8) + u;
  const float2* hp = hl + (kh << 7);
  const int lrow = grp & 1, lsh = grp >> 1;   // logits decomposition
  const int mrow = grp & 1, mkk = grp >> 1;   // matvec decomposition (row, k/s-half)

  const float* rgL = refg + ((size_t)(b0+lrow)*S_ + lsh*50)*H_;
  const float* rpL = refp + ((size_t)(b0+lrow)*S_ + lsh*50)*H_;

  // ---- prologue: gates(0) from h_in (exact r9 serial chain, k=0..127)
  {
    float2 A0 = make_float2(0.f,0.f), A1 = make_float2(0.f,0.f);
    #pragma unroll 8
    for (int k = 0; k < 128; ++k) {
      const float2 w  = wp[(size_t)k << 9];
      const float2 hv = hp[k];
      A0.x += hv.x*w.x; A0.y += hv.x*w.y;
      A1.x += hv.y*w.x; A1.y += hv.y*w.y;
    }
    redB[grp][0][u] = A0; redB[grp][1][u] = A1;
  }
  __syncthreads();

  #pragma unroll 1
  for (int t = 0; t < 100; ++t) {
    // ---- S1: LSTM pointwise (grp0; gates partials from redB; x rank-2 factored)
    if (grp == 0) {
      const float2 r00 = redB[0][0][u], r10 = redB[1][0][u], r20 = redB[2][0][u], r30 = redB[3][0][u];
      const float2 r01 = redB[0][1][u], r11 = redB[1][1][u], r21 = redB[2][1][u], r31 = redB[3][1][u];
      float2 h2;
      {
        float xi, xf, xg, xo;
        const int s = sel_l[0];
        if (s < 0) { xi = Psv.x; xf = Psv.y; xg = Psv.z; xo = Psv.w; }
        else {
          const float ca = cl[0][s], cb = cl[0][100+s];
          xi = ca*P0v.x + cb*P1v.x; xf = ca*P0v.y + cb*P1v.y;
          xg = ca*P0v.z + cb*P1v.z; xo = ca*P0v.w + cb*P1v.w;
        }
        const float gi = xi + r00.x + r10.x + bq.x;
        const float gf = xf + r00.y + r10.y + bq.y;
        const float gg = xg + r20.x + r30.x + bq.z;
        const float go = xo + r20.y + r30.y + bq.w;
        const float cN = sigmoidf_(gf)*c0s + sigmoidf_(gi)*tanhf(gg);
        c0s = cN; h2.x = sigmoidf_(go)*tanhf(cN);
      }
      {
        float xi, xf, xg, xo;
        const int s = sel_l[1];
        if (s < 0) { xi = Psv.x; xf = Psv.y; xg = Psv.z; xo = Psv.w; }
        else {
          const float ca = cl[1][s], cb = cl[1][100+s];
          xi = ca*P0v.x + cb*P1v.x; xf = ca*P0v.y + cb*P1v.y;
          xg = ca*P0v.z + cb*P1v.z; xo = ca*P0v.w + cb*P1v.w;
        }
        const float gi = xi + r01.x + r11.x + bq.x;
        const float gf = xf + r01.y + r11.y + bq.y;
        const float gg = xg + r21.x + r31.x + bq.z;
        const float go = xo + r21.y + r31.y + bq.w;
        const float cN = sigmoidf_(gf)*c1s + sigmoidf_(gi)*tanhf(gg);
        c1s = cN; h2.y = sigmoidf_(go)*tanhf(cN);
      }
      hl[u] = h2;
    }
    __syncthreads();                               // B1

    // ---- gates(t+1) accumulators, live across the next three phases
    float2 gA0 = make_float2(0.f,0.f), gA1 = make_float2(0.f,0.f);

    // ---- S2: gates chunk A (k=0..63) + qq = g_bq + h @ gWq^T
    #pragma unroll 8
    for (int k = 0; k < 64; ++k) {
      const float2 w  = wp[(size_t)k << 9];
      const float2 hv = hp[k];
      gA0.x += hv.x*w.x; gA0.y += hv.x*w.y;
      gA1.x += hv.y*w.x; gA1.y += hv.y*w.y;
    }
    {
      float qa = (mkk == 0) ? gbqv : 0.f, qb = 0.f;
      const float* hb = (const float*)hl + mrow;
      const float* wq = gWqT + ((size_t)mkk << 15) + u;
      #pragma unroll 8
      for (int k = 0; k < 64; ++k) {
        qa += hb[((mkk << 7) + k) << 1]      * wq[(size_t)k << 8];
        qb += hb[((mkk << 7) + 64 + k) << 1] * wq[(size_t)(64 + k) << 8];
      }
      qq_l[mkk][mrow][u] = qa + qb;
    }
    __syncthreads();                               // B2

    // ---- S3: glimpse logits (row, s-half); mask-skip; qq combined from partials
    {
      const int* mk = mask_l[lrow];
      const float* q0 = qq_l[0][lrow];
      const float* q1 = qq_l[1][lrow];
      for (int is = 0; is < 13; ++is) {
        const int so = is*4 + wv2;
        if (so < 50) {
          const int s = lsh*50 + so;
          if (mk[s]) {
            if (lane == 0) lg_l[lrow][s] = -INFINITY;
          } else {
            float pa = 0.f;
            #pragma unroll
            for (int j = 0; j < 4; ++j) {
              const int hh = lane + 64*j;
              pa += gv_l[hh] * tanh_(q0[hh] + q1[hh] + rgL[(size_t)so*256 + hh]);
            }
            pa = wsum_(pa);
            if (lane == 0) lg_l[lrow][s] = pa;
          }
        }
      }
    }
    __syncthreads();                               // B3

    // ---- S4: glimpse softmax (wave 0 -> row0, wave 8 -> row1)
    if ((wv & 7) == 0) {
      const int row = wv >> 3;
      const float v0 = lg_l[row][lane];
      const float v1 = (lane + 64 < S_) ? lg_l[row][lane + 64] : -INFINITY;
      const float m  = wmax_(fmaxf(v0, v1));
      const float ea = expf(v0 - m);
      const float eb = (lane + 64 < S_) ? expf(v1 - m) : 0.f;
      const float sm = wsum_(ea + eb);
      al_l[row][lane] = ea / sm;
      if (lane + 64 < S_) al_l[row][lane + 64] = eb / sm;
    }
    __syncthreads();                               // B4

    // ---- S5: gates chunk B (k=64..95) + q = sum_s alpha[s] * enc[b,s,:]
    #pragma unroll 8
    for (int k = 64; k < 96; ++k) {
      const float2 w  = wp[(size_t)k << 9];
      const float2 hv = hp[k];
      gA0.x += hv.x*w.x; gA0.y += hv.x*w.y;
      gA1.x += hv.y*w.x; gA1.y += hv.y*w.y;
    }
    {
      const float* ebp = enc + (size_t)(b0+mrow)*25600 + ((size_t)(mkk*50) << 8) + u;
      const float* av  = al_l[mrow] + mkk*50;
      float aa = 0.f, ab = 0.f;
      #pragma unroll 5
      for (int s = 0; s < 25; ++s) {
        aa += av[s]      * ebp[(size_t)s << 8];
        ab += av[25 + s] * ebp[(size_t)(25 + s) << 8];
      }
      qp_l[mkk][mrow][u] = aa + ab;
    }
    __syncthreads();                               // B5

    // ---- S6: gates chunk C (k=96..127) + pq = p_bq + q @ pWq^T; write redB
    #pragma unroll 8
    for (int k = 96; k < 128; ++k) {
      const float2 w  = wp[(size_t)k << 9];
      const float2 hv = hp[k];
      gA0.x += hv.x*w.x; gA0.y += hv.x*w.y;
      gA1.x += hv.y*w.x; gA1.y += hv.y*w.y;
    }
    redB[grp][0][u] = gA0; redB[grp][1][u] = gA1;
    {
      float qa = (mkk == 0) ? pbqv : 0.f, qb = 0.f;
      const float* wq = pWqT + ((size_t)mkk << 15) + u;
      const float* q0 = qp_l[0][mrow] + (mkk << 7);
      const float* q1 = qp_l[1][mrow] + (mkk << 7);
      #pragma unroll 8
      for (int k = 0; k < 64; ++k) {
        qa += (q0[k]      + q1[k])      * wq[(size_t)k << 8];
        qb += (q0[64 + k] + q1[64 + k]) * wq[(size_t)(64 + k) << 8];
      }
      pq_l[mkk][mrow][u] = qa + qb;
    }
    __syncthreads();                               // B6

    // ---- S7: pointer logits: 10*tanh(attn); mask-skip; pq combined from partials
    {
      const int* mk = mask_l[lrow];
      const float* q0 = pq_l[0][lrow];
      const float* q1 = pq_l[1][lrow];
      for (int is = 0; is < 13; ++is) {
        const int so = is*4 + wv2;
        if (so < 50) {
          const int s = lsh*50 + so;
          if (mk[s]) {
            if (lane == 0) lp_l[lrow][s] = -INFINITY;
          } else {
            float pa = 0.f;
            #pragma unroll
            for (int j = 0; j < 4; ++j) {
              const int hh = lane + 64*j;
              pa += pv_l[hh] * tanh_(q0[hh] + q1[hh] + rpL[(size_t)so*256 + hh]);
            }
            pa = wsum_(pa);
            if (lane == 0) lp_l[lrow][s] = 10.0f * tanhf(pa);
          }
        }
      }
    }
    __syncthreads();                               // B7

    // ---- S8: pointer softmax + gumbel-argmax sampling
    if ((wv & 7) == 0) {
      const int row = wv >> 3;
      const int b   = b0 + row;
      const float v0 = lp_l[row][lane];
      const float v1 = (lane + 64 < S_) ? lp_l[row][lane + 64] : -INFINITY;
      const float m  = wmax_(fmaxf(v0, v1));
      const float ea = expf(v0 - m);
      const float eb = (lane + 64 < S_) ? expf(v1 - m) : 0.f;
      const float sm = wsum_(ea + eb);
      float* po = probs_out + ((size_t)t*B_ + b)*S_;
      po[lane] = ea / sm;
      if (lane + 64 < S_) po[lane + 64] = eb / sm;

      uint32_t k0, k1; threefry2x32_(0u, 1u, 0u, (uint32_t)t, k0, k1);
      uint32_t r0, r1;
      threefry2x32_(k0, k1, 0u, (uint32_t)(b*S_ + lane), r0, r1);
      float z0 = v0 + gumbel_bits_(r0 ^ r1);
      float z1 = -INFINITY;
      if (lane + 64 < S_) {
        uint32_t q0b, q1b;
        threefry2x32_(k0, k1, 0u, (uint32_t)(b*S_ + lane + 64), q0b, q1b);
        z1 = v1 + gumbel_bits_(q0b ^ q1b);
      }
      float bvv; int bi;
      if (z1 > z0) { bvv = z1; bi = lane + 64; } else { bvv = z0; bi = lane; }
      #pragma unroll
      for (int d = 32; d > 0; d >>= 1) {
        const float ov = __shfl_xor(bvv, d, 64);
        const int   oi = __shfl_xor(bi, d, 64);
        if (ov > bvv || (ov == bvv && oi < bi)) { bvv = ov; bi = oi; }
      }
      if (lane == 0) {
        idx_out[t*B_ + b] = (float)bi;
        sel_l[row] = bi;
        mask_l[row][bi] = 1;
      }
    }
    __syncthreads();                               // B8
  }
}

extern "C" void kernel_launch(void* const* d_in, const int* in_sizes, int n_in,
                              void* d_out, int out_size, void* d_ws, size_t ws_size,
                              hipStream_t stream) {
  (void)in_sizes; (void)n_in; (void)out_size; (void)ws_size;
  const float* inputs = (const float*)d_in[0];
  const float* emb    = (const float*)d_in[1];
  const float* eWih   = (const float*)d_in[2];
  const float* eWhh   = (const float*)d_in[3];
  const float* ebih   = (const float*)d_in[4];
  const float* ebhh   = (const float*)d_in[5];
  const float* dWih   = (const float*)d_in[6];
  const float* dWhh   = (const float*)d_in[7];
  const float* dbih   = (const float*)d_in[8];
  const float* dbhh   = (const float*)d_in[9];
  const float* gWq    = (const float*)d_in[10];
  const float* gbq    = (const float*)d_in[11];
  const float* gWr    = (const float*)d_in[12];
  const float* gbr    = (const float*)d_in[13];
  const float* gV     = (const float*)d_in[14];
  const float* pWq    = (const float*)d_in[15];
  const float* pbq    = (const float*)d_in[16];
  const float* pWr    = (const float*)d_in[17];
  const float* pbr    = (const float*)d_in[18];
  const float* pV     = (const float*)d_in[19];
  const float* start  = (const float*)d_in[20];

  float* ws = (float*)d_ws;
  size_t o = 0;
  float* WtE  = ws + o; o += (size_t)256*1024;   // encoder quad (Whh only)
  float* WhD  = ws + o; o += (size_t)256*1024;   // decoder pair layout (Whh only)
  float* b4E  = ws + o; o += 1024;
  float* b4D  = ws + o; o += 1024;
  float* PE0  = ws + o; o += 1024;
  float* PE1  = ws + o; o += 1024;
  float* PD0  = ws + o; o += 1024;
  float* PD1  = ws + o; o += 1024;
  float* PDs  = ws + o; o += 1024;
  float* gWqT = ws + o; o += 65536;
  float* pWqT = ws + o; o += 65536;
  float* gWrT = ws + o; o += 65536;
  float* pWrT = ws + o; o += 65536;
  float* enc  = ws + o; o += (size_t)B_*S_*H_;
  float* refg = ws + o; o += (size_t)B_*S_*H_;
  float* refp = ws + o; o += (size_t)B_*S_*H_;
  float* hbuf = ws + o; o += (size_t)B_*H_;
  float* cbuf = ws + o; o += (size_t)B_*H_;

  float* probs = (float*)d_out;
  float* idxo  = probs + (size_t)S_*B_*S_;

  prep_whQ<<<1024,256,0,stream>>>(eWhh, WtE);
  prep_wh_pair<<<1024,256,0,stream>>>(dWhh, WhD);
  prep_P<<<4,256,0,stream>>>(eWih, emb,       PE0);
  prep_P<<<4,256,0,stream>>>(eWih, emb + 256, PE1);
  prep_P<<<4,256,0,stream>>>(dWih, emb,       PD0);
  prep_P<<<4,256,0,stream>>>(dWih, emb + 256, PD1);
  prep_P<<<4,256,0,stream>>>(dWih, start,     PDs);
  prep_bias4<<<4,256,0,stream>>>(ebih, ebhh, b4E);
  prep_bias4<<<4,256,0,stream>>>(dbih, dbhh, b4D);
  transpose256<<<256,256,0,stream>>>(gWq, gWqT);
  transpose256<<<256,256,0,stream>>>(pWq, pWqT);
  transpose256<<<256,256,0,stream>>>(gWr, gWrT);
  transpose256<<<256,256,0,stream>>>(pWr, pWrT);

  encoder_kernel<<<128,512,0,stream>>>(WtE, b4E, PE0, PE1, inputs, enc, hbuf, cbuf);

  gemm_ref<<<dim3(400,2),256,0,stream>>>(enc, gWrT, gbr, refg);
  gemm_ref<<<dim3(400,2),256,0,stream>>>(enc, pWrT, pbr, refp);

  decoder_kernel<<<256,1024,0,stream>>>(WhD, b4D, PD0, PD1, PDs, inputs,
                                        enc, refg, refp,
                                        gWqT, gbq, gV, pWqT, pbq, pV,
                                        hbuf, cbuf, probs, idxo);
}